// Round 2
// baseline (866.201 us; speedup 1.0000x reference)
//
#include <hip/hip_runtime.h>

#define B_TOTAL 131072
#define NCOUNT 8
#define NL1 512
#define NL2 16
#define NL3 32
#define W_WIN 512
#define BLK 256
#define SPLIT 4
#define NGROUPS (BLK / SPLIT)   // 64 groups per block

__global__ __launch_bounds__(BLK) void nnue_fused_kernel(
    const float* __restrict__ accum,
    const float* __restrict__ us,
    const float* __restrict__ l1_w,
    const float* __restrict__ l1_b,
    const float* __restrict__ l2_w,
    const float* __restrict__ l2_b,
    const float* __restrict__ out_w,
    const float* __restrict__ out_b,
    const int*   __restrict__ psqt_indices,
    const int*   __restrict__ lsi,
    float*       __restrict__ out)
{
    __shared__ int list[W_WIN];
    __shared__ int cnt;
    const int l    = blockIdx.y;          // stack index owned by this block
    const int base = blockIdx.x * W_WIN;

    if (threadIdx.x == 0) cnt = 0;
    __syncthreads();

    // Phase 1: compact sample ids in this window matching our stack index.
    for (int i = threadIdx.x; i < W_WIN; i += BLK) {
        int s = base + i;
        if (lsi[s] == l) {
            int p = atomicAdd(&cnt, 1);
            list[p] = s;
        }
    }
    __syncthreads();
    const int n = cnt;

    const int g   = threadIdx.x >> 2;     // group id (one sample per group)
    const int sub = threadIdx.x & 3;      // lane within group: K-quarter

    // Weight base for this stack index (uniform per block).
    const float4* __restrict__ w4 = (const float4*)l1_w + (size_t)l * NL2 * 256;

    for (int t = g; t < n; t += NGROUPS) {
        const int s = list[t];
        const float* __restrict__ row   = accum + (size_t)s * 1040;
        const float4* __restrict__ row4 = (const float4*)row;

        float acc[NL2];
        #pragma unroll
        for (int j = 0; j < NL2; ++j) acc[j] = 0.0f;

        // Each sub-lane: interleaved quarter of K.
        // First half : row floats [0,512)    -> chunks 0..127,   weight chunks 0..127
        // Second half: row floats [520,1032) -> chunks 130..257, weight chunks 128..255
        #pragma unroll 2
        for (int i = 0; i < 32; ++i) {
            const int c = sub + 4 * i;
            float4 a = row4[c];
            float4 b = row4[130 + c];
            #pragma unroll
            for (int j = 0; j < NL2; ++j) {
                float4 wA = w4[j * 256 + c];
                float4 wB = w4[j * 256 + 128 + c];
                acc[j] += a.x * wA.x + a.y * wA.y + a.z * wA.z + a.w * wA.w
                        + b.x * wB.x + b.y * wB.y + b.z * wB.z + b.w * wB.w;
            }
        }

        // Reduce the 16 partial sums across the 4 sub-lanes (all lanes get full sum).
        #pragma unroll
        for (int j = 0; j < NL2; ++j) {
            acc[j] += __shfl_xor(acc[j], 1);
            acc[j] += __shfl_xor(acc[j], 2);
        }

        // Bias + clip (computed redundantly on all 4 lanes, cheap).
        float l1y[NL2];
        #pragma unroll
        for (int j = 0; j < NL2; ++j)
            l1y[j] = fminf(fmaxf(acc[j] + l1_b[l * NL2 + j], 0.0f), 1.0f);

        // L2 (32x16) + out (1x32): each sub-lane handles 8 of the 32 L2 rows.
        const float* __restrict__ w2 = l2_w + (size_t)l * NL3 * NL2;
        float part = 0.0f;
        #pragma unroll
        for (int jj = 0; jj < 8; ++jj) {
            const int j = sub * 8 + jj;
            float s2 = l2_b[l * NL3 + j];
            #pragma unroll
            for (int k = 0; k < NL2; ++k) s2 += l1y[k] * w2[j * NL2 + k];
            float l2y = fminf(fmaxf(s2, 0.0f), 1.0f);
            part += l2y * out_w[l * NL3 + j];
        }
        part += __shfl_xor(part, 1);
        part += __shfl_xor(part, 2);

        if (sub == 0) {
            int pi = psqt_indices[s];
            float wp = row[NL1 + pi];                 // w_psqt
            float bp = row[2 * NL1 + NCOUNT + pi];    // b_psqt
            out[s] = part + out_b[l] + (wp - bp) * (us[s] - 0.5f);
        }
    }
}

extern "C" void kernel_launch(void* const* d_in, const int* in_sizes, int n_in,
                              void* d_out, int out_size, void* d_ws, size_t ws_size,
                              hipStream_t stream) {
    const float* accum = (const float*)d_in[0];
    const float* us    = (const float*)d_in[1];
    const float* l1_w  = (const float*)d_in[2];
    const float* l1_b  = (const float*)d_in[3];
    const float* l2_w  = (const float*)d_in[4];
    const float* l2_b  = (const float*)d_in[5];
    const float* out_w = (const float*)d_in[6];
    const float* out_b = (const float*)d_in[7];
    const int*   psqt  = (const int*)d_in[8];
    const int*   lsi   = (const int*)d_in[9];
    float* out = (float*)d_out;

    dim3 grid(B_TOTAL / W_WIN, NCOUNT);
    nnue_fused_kernel<<<grid, BLK, 0, stream>>>(
        accum, us, l1_w, l1_b, l2_w, l2_b, out_w, out_b, psqt, lsi, out);
}

// Round 3
// 153.567 us; speedup vs baseline: 5.6406x; 5.6406x over previous
//
#include <hip/hip_runtime.h>
#include <hip/hip_bf16.h>

#define NCOUNT 8
#define B_TOTAL 131072
#define W_WIN 1024
#define BLK 256

typedef __attribute__((ext_vector_type(8))) short bf16x8;
typedef __attribute__((ext_vector_type(4))) float f32x4;
typedef __attribute__((ext_vector_type(16))) float f32x16;

__device__ inline short bf_cvt(float x) {
    __hip_bfloat16 h = __float2bfloat16(x);   // RNE
    return *reinterpret_cast<short*>(&h);
}
__device__ inline bf16x8 cvt8(float4 a, float4 b) {
    bf16x8 r;
    r[0] = bf_cvt(a.x); r[1] = bf_cvt(a.y); r[2] = bf_cvt(a.z); r[3] = bf_cvt(a.w);
    r[4] = bf_cvt(b.x); r[5] = bf_cvt(b.y); r[6] = bf_cvt(b.z); r[7] = bf_cvt(b.w);
    return r;
}

__global__ __launch_bounds__(BLK, 4) void nnue_mfma_kernel(
    const float* __restrict__ accum,
    const float* __restrict__ us,
    const float* __restrict__ l1_w,
    const float* __restrict__ l1_b,
    const float* __restrict__ l2_w,
    const float* __restrict__ l2_b,
    const float* __restrict__ out_w,
    const float* __restrict__ out_b,
    const int*   __restrict__ psqt_indices,
    const int*   __restrict__ lsi,
    float*       __restrict__ out)
{
    __shared__ int list[W_WIN];
    __shared__ int cnt;
    __shared__ __align__(16) float l1y[4][16 * 20];   // per-wave 16x16 tile, stride 20 (bank spread)

    const int l    = blockIdx.y;
    const int base = blockIdx.x * W_WIN;
    const int lane = threadIdx.x & 63;
    const int wid  = threadIdx.x >> 6;

    if (threadIdx.x == 0) cnt = 0;
    __syncthreads();
    for (int i = threadIdx.x; i < W_WIN; i += BLK) {
        if (lsi[base + i] == l) list[atomicAdd(&cnt, 1)] = base + i;
    }
    __syncthreads();
    const int n = cnt;
    if (n == 0) return;

    // ---- persistent per-lane state ----
    const int jlow  = lane & 15;    // L1 frag: sample slot (A) / weight row j (B) / D1 col
    const int g     = lane >> 4;    // L1 frag k-group
    const int col32 = lane & 31;    // L2 MFMA: A row j2 / D2 col (sample)
    const int h     = lane >> 5;    // L2 frag k-half

    // W2 as persistent A-frag (32x16, K=16): lane holds row col32, k = h*8+e
    {
        // nothing
    }
    const float* w2row = l2_w + ((size_t)l * 32 + col32) * 16 + h * 8;
    const bf16x8 w2frag = cvt8(*(const float4*)(w2row), *(const float4*)(w2row + 4));

    // per-reg j2 tables for D2 epilogue: j2 = (r&3) + 8*(r>>2) + 4*h
    float w3v[16], b2v[16];
    #pragma unroll
    for (int r = 0; r < 16; ++r) {
        int j2 = (r & 3) + 8 * (r >> 2) + 4 * h;
        w3v[r] = out_w[l * 32 + j2];
        b2v[r] = l2_b[l * 32 + j2];
    }
    const float l1bias = l1_b[l * 16 + jlow];
    const float outb   = out_b[l];
    const float* wrow  = l1_w + (((size_t)l * 16 + jlow) << 10);  // weight row j, 1024 cols

    // ---- tile loop: each wave owns 16-sample tiles ----
    for (int tb = wid * 16; tb < n; tb += 64) {
        const int mIdx = tb + jlow;
        const int s    = list[mIdx < n ? mIdx : n - 1];
        const float* row = accum + (size_t)s * 1040;

        f32x4 acc = {0.f, 0.f, 0.f, 0.f};
        #pragma unroll 4
        for (int t = 0; t < 32; ++t) {
            const int kf = t * 32 + g * 8;            // logical k in [0,1024)
            const int ra = kf + ((kf >> 9) << 3);     // skip the 8-float psqt gap at 512
            float4 a0 = *(const float4*)(row + ra);
            float4 a1 = *(const float4*)(row + ra + 4);
            float4 b0 = *(const float4*)(wrow + kf);
            float4 b1 = *(const float4*)(wrow + kf + 4);
            acc = __builtin_amdgcn_mfma_f32_16x16x32_bf16(cvt8(a0, a1), cvt8(b0, b1), acc, 0, 0, 0);
        }

        // L1 activation -> per-wave LDS tile (D1: col=jlow=j, row=g*4+r=sample)
        float* ly = l1y[wid];
        #pragma unroll
        for (int r = 0; r < 4; ++r) {
            float v = fminf(fmaxf(acc[r] + l1bias, 0.f), 1.f);
            ly[(g * 4 + r) * 20 + jlow] = v;
        }
        __builtin_amdgcn_wave_barrier();
        asm volatile("s_waitcnt lgkmcnt(0)" ::: "memory");

        // B2 frag: transposed read — lane = sample col32 (&15: cols 16-31 are dummies), k=j=h*8+e
        const float* lyr = ly + (col32 & 15) * 20 + h * 8;
        float4 y0 = *(const float4*)(lyr);
        float4 y1 = *(const float4*)(lyr + 4);
        __builtin_amdgcn_wave_barrier();
        const bf16x8 b2frag = cvt8(y0, y1);

        f32x16 acc2 = {};
        acc2 = __builtin_amdgcn_mfma_f32_32x32x16_bf16(w2frag, b2frag, acc2, 0, 0, 0);

        // L2 activation + out layer, then combine the two j2-halves (lane ^ 32)
        float partial = 0.f;
        #pragma unroll
        for (int r = 0; r < 16; ++r) {
            float v = fminf(fmaxf(acc2[r] + b2v[r], 0.f), 1.f);
            partial += v * w3v[r];
        }
        partial += __shfl_xor(partial, 32);

        if (lane < 16 && mIdx < n) {
            const int pi = psqt_indices[s];
            const float wp = row[512 + pi];    // w_psqt
            const float bp = row[1032 + pi];   // b_psqt
            out[s] = partial + outb + (wp - bp) * (us[s] - 0.5f);
        }
    }
}

extern "C" void kernel_launch(void* const* d_in, const int* in_sizes, int n_in,
                              void* d_out, int out_size, void* d_ws, size_t ws_size,
                              hipStream_t stream) {
    const float* accum = (const float*)d_in[0];
    const float* us    = (const float*)d_in[1];
    const float* l1_w  = (const float*)d_in[2];
    const float* l1_b  = (const float*)d_in[3];
    const float* l2_w  = (const float*)d_in[4];
    const float* l2_b  = (const float*)d_in[5];
    const float* out_w = (const float*)d_in[6];
    const float* out_b = (const float*)d_in[7];
    const int*   psqt  = (const int*)d_in[8];
    const int*   lsi   = (const int*)d_in[9];
    float* out = (float*)d_out;

    dim3 grid(B_TOTAL / W_WIN, NCOUNT);
    nnue_mfma_kernel<<<grid, BLK, 0, stream>>>(
        accum, us, l1_w, l1_b, l2_w, l2_b, out_w, out_b, psqt, lsi, out);
}

// Round 4
// 124.298 us; speedup vs baseline: 6.9687x; 1.2355x over previous
//
#include <hip/hip_runtime.h>
#include <hip/hip_bf16.h>

#define NCOUNT 8
#define B_TOTAL 131072
#define W_WIN 1024
#define BLK 256
#define AT_STRIDE 1048   // bf16 elems per At row: 1024 + 24 pad (16B-aligned, stride%32words=12)

typedef __attribute__((ext_vector_type(8))) short bf16x8;
typedef __attribute__((ext_vector_type(4))) float f32x4;
typedef __attribute__((ext_vector_type(16))) float f32x16;

__device__ inline short bf_cvt(float x) {
    __hip_bfloat16 h = __float2bfloat16(x);   // RNE
    return *reinterpret_cast<short*>(&h);
}
__device__ inline bf16x8 cvt8(float4 a, float4 b) {
    bf16x8 r;
    r[0] = bf_cvt(a.x); r[1] = bf_cvt(a.y); r[2] = bf_cvt(a.z); r[3] = bf_cvt(a.w);
    r[4] = bf_cvt(b.x); r[5] = bf_cvt(b.y); r[6] = bf_cvt(b.z); r[7] = bf_cvt(b.w);
    return r;
}

__global__ __launch_bounds__(BLK, 3) void nnue_mfma_kernel(
    const float* __restrict__ accum,
    const float* __restrict__ us,
    const float* __restrict__ l1_w,
    const float* __restrict__ l1_b,
    const float* __restrict__ l2_w,
    const float* __restrict__ l2_b,
    const float* __restrict__ out_w,
    const float* __restrict__ out_b,
    const int*   __restrict__ psqt_indices,
    const int*   __restrict__ lsi,
    float*       __restrict__ out)
{
    __shared__ int list[W_WIN];
    __shared__ int cnt;
    __shared__ __align__(16) short At[16][AT_STRIDE];     // bf16 tile, gap-free
    __shared__ __align__(16) float psq[16][16];           // [r][0:8)=w_psqt, [8:16)=b_psqt
    __shared__ __align__(16) float l1part[4][64][4];      // split-K partials
    __shared__ __align__(16) float l1y[16 * 20];          // wave-0 activation exchange

    const int l    = blockIdx.y;
    const int base = blockIdx.x * W_WIN;
    const int tid  = threadIdx.x;
    const int lane = tid & 63;
    const int wid  = tid >> 6;

    if (tid == 0) cnt = 0;
    __syncthreads();
    for (int i = tid; i < W_WIN; i += BLK)
        if (lsi[base + i] == l) list[atomicAdd(&cnt, 1)] = base + i;
    __syncthreads();
    const int n = cnt;
    if (n == 0) return;

    const int jlow  = lane & 15;
    const int g     = lane >> 4;
    const int col32 = lane & 31;
    const int h     = lane >> 5;

    // ---- persistent weights in registers ----
    // L1: this wave owns K range [wid*256, wid*256+256): t = wid*8 + i
    const float* wrow = l1_w + (((size_t)l * 16 + jlow) << 10);
    bf16x8 wfrag[8];
    #pragma unroll
    for (int i = 0; i < 8; ++i) {
        const int kf = (wid * 8 + i) * 32 + g * 8;
        wfrag[i] = cvt8(*(const float4*)(wrow + kf), *(const float4*)(wrow + kf + 4));
    }
    const float* w2row = l2_w + ((size_t)l * 32 + col32) * 16 + h * 8;
    const bf16x8 w2frag = cvt8(*(const float4*)(w2row), *(const float4*)(w2row + 4));
    float w3v[16], b2v[16];
    #pragma unroll
    for (int r = 0; r < 16; ++r) {
        int j2 = (r & 3) + 8 * (r >> 2) + 4 * h;
        w3v[r] = out_w[l * 32 + j2];
        b2v[r] = l2_b[l * 32 + j2];
    }
    const float l1bias = l1_b[l * 16 + jlow];
    const float outb   = out_b[l];

    const int srow  = tid >> 5;   // 0..7 (staging row within pass)
    const int scol8 = tid & 31;   // 8-float chunk lane

    for (int tb = 0; tb < n; tb += 16) {
        // ---- stage 16 rows -> At (bf16, gap removed), full-row bursts ----
        #pragma unroll
        for (int rr = 0; rr < 2; ++rr) {
            const int row = rr * 8 + srow;
            const int mi  = tb + row;
            const float* src = accum + (size_t)list[mi < n ? mi : n - 1] * 1040;
            #pragma unroll
            for (int p = 0; p < 4; ++p) {
                const int col = scol8 + 32 * p;              // [0,128) 8-float chunks
                const int sf  = 8 * col + (col >= 64 ? 8 : 0);  // skip psqt gap at 512
                float4 a0 = *(const float4*)(src + sf);
                float4 a1 = *(const float4*)(src + sf + 4);
                *(bf16x8*)&At[row][8 * col] = cvt8(a0, a1);
            }
        }
        if (tid < 64) {   // stage psqt floats: [512,520) and [1032,1040)
            const int pr = tid >> 2, part = tid & 3;
            const int mi = tb + pr;
            const float* src = accum + (size_t)list[mi < n ? mi : n - 1] * 1040;
            const int sf = (part < 2) ? (512 + 4 * part) : (1032 + 4 * (part - 2));
            *(float4*)&psq[pr][part * 4] = *(const float4*)(src + sf);
        }
        __syncthreads();

        // ---- split-K MFMA: 8 iters over this wave's K-quarter ----
        f32x4 acc = {0.f, 0.f, 0.f, 0.f};
        #pragma unroll
        for (int i = 0; i < 8; ++i) {
            const int kf = (wid * 8 + i) * 32 + g * 8;
            bf16x8 afrag = *(const bf16x8*)&At[jlow][kf];
            acc = __builtin_amdgcn_mfma_f32_16x16x32_bf16(afrag, wfrag[i], acc, 0, 0, 0);
        }
        *(f32x4*)&l1part[wid][lane][0] = acc;
        __syncthreads();

        if (wid == 0) {
            f32x4 t0 = *(const f32x4*)&l1part[0][lane][0];
            f32x4 t1 = *(const f32x4*)&l1part[1][lane][0];
            f32x4 t2 = *(const f32x4*)&l1part[2][lane][0];
            f32x4 t3 = *(const f32x4*)&l1part[3][lane][0];
            #pragma unroll
            for (int r = 0; r < 4; ++r) {
                float v = fminf(fmaxf(t0[r] + t1[r] + t2[r] + t3[r] + l1bias, 0.f), 1.f);
                l1y[(g * 4 + r) * 20 + jlow] = v;
            }
            __builtin_amdgcn_wave_barrier();
            asm volatile("s_waitcnt lgkmcnt(0)" ::: "memory");

            const float* lyr = l1y + (col32 & 15) * 20 + h * 8;
            float4 y0 = *(const float4*)(lyr);
            float4 y1 = *(const float4*)(lyr + 4);
            const bf16x8 b2frag = cvt8(y0, y1);

            f32x16 acc2 = {};
            acc2 = __builtin_amdgcn_mfma_f32_32x32x16_bf16(w2frag, b2frag, acc2, 0, 0, 0);

            float partial = 0.f;
            #pragma unroll
            for (int r = 0; r < 16; ++r) {
                float v = fminf(fmaxf(acc2[r] + b2v[r], 0.f), 1.f);
                partial += v * w3v[r];
            }
            partial += __shfl_xor(partial, 32);

            if (lane < 16 && tb + jlow < n) {
                const int s  = list[tb + jlow];
                const int pi = psqt_indices[s];
                const float wp = psq[jlow][pi];
                const float bp = psq[jlow][8 + pi];
                out[s] = partial + outb + (wp - bp) * (us[s] - 0.5f);
            }
        }
        __syncthreads();   // At/psq/l1part safe to overwrite next tile
    }
}

extern "C" void kernel_launch(void* const* d_in, const int* in_sizes, int n_in,
                              void* d_out, int out_size, void* d_ws, size_t ws_size,
                              hipStream_t stream) {
    const float* accum = (const float*)d_in[0];
    const float* us    = (const float*)d_in[1];
    const float* l1_w  = (const float*)d_in[2];
    const float* l1_b  = (const float*)d_in[3];
    const float* l2_w  = (const float*)d_in[4];
    const float* l2_b  = (const float*)d_in[5];
    const float* out_w = (const float*)d_in[6];
    const float* out_b = (const float*)d_in[7];
    const int*   psqt  = (const int*)d_in[8];
    const int*   lsi   = (const int*)d_in[9];
    float* out = (float*)d_out;

    dim3 grid(B_TOTAL / W_WIN, NCOUNT);
    nnue_mfma_kernel<<<grid, BLK, 0, stream>>>(
        accum, us, l1_w, l1_b, l2_w, l2_b, out_w, out_b, psqt, lsi, out);
}

// Round 5
// 111.006 us; speedup vs baseline: 7.8032x; 1.1197x over previous
//
#include <hip/hip_runtime.h>
#include <hip/hip_bf16.h>

#define NCOUNT 8
#define B_TOTAL 131072
#define W_WIN 1024
#define BLK 256
#define AT_STRIDE 1048   // bf16 elems per At row: 1024 + 24 pad

typedef __attribute__((ext_vector_type(8))) short bf16x8;
typedef __attribute__((ext_vector_type(4))) float f32x4;
typedef __attribute__((ext_vector_type(16))) float f32x16;

__device__ inline short bf_cvt(float x) {
    __hip_bfloat16 h = __float2bfloat16(x);   // RNE
    return *reinterpret_cast<short*>(&h);
}
__device__ inline bf16x8 cvt8(float4 a, float4 b) {
    bf16x8 r;
    r[0] = bf_cvt(a.x); r[1] = bf_cvt(a.y); r[2] = bf_cvt(a.z); r[3] = bf_cvt(a.w);
    r[4] = bf_cvt(b.x); r[5] = bf_cvt(b.y); r[6] = bf_cvt(b.z); r[7] = bf_cvt(b.w);
    return r;
}

__global__ __launch_bounds__(BLK, 2) void nnue_mfma_kernel(
    const float* __restrict__ accum,
    const float* __restrict__ us,
    const float* __restrict__ l1_w,
    const float* __restrict__ l1_b,
    const float* __restrict__ l2_w,
    const float* __restrict__ l2_b,
    const float* __restrict__ out_w,
    const float* __restrict__ out_b,
    const int*   __restrict__ psqt_indices,
    const int*   __restrict__ lsi,
    float*       __restrict__ out)
{
    __shared__ int list[W_WIN];
    __shared__ int cnt;
    __shared__ __align__(16) short At[16][AT_STRIDE];     // bf16 tile, gap-free
    __shared__ __align__(16) float psq[2][16][16];        // double-buffered psqt floats
    __shared__ __align__(16) float l1part[4][64][4];      // split-K partials
    __shared__ __align__(16) float l1y[16 * 20];          // wave-0 activation exchange

    const int l    = blockIdx.y;
    const int base = blockIdx.x * W_WIN;
    const int tid  = threadIdx.x;
    const int lane = tid & 63;
    const int wid  = tid >> 6;

    if (tid == 0) cnt = 0;
    __syncthreads();
    for (int i = tid; i < W_WIN; i += BLK)
        if (lsi[base + i] == l) list[atomicAdd(&cnt, 1)] = base + i;
    __syncthreads();
    const int n = cnt;
    if (n == 0) return;

    const int jlow  = lane & 15;
    const int g     = lane >> 4;
    const int col32 = lane & 31;
    const int h     = lane >> 5;

    // ---- persistent weights in registers ----
    const float* wrow = l1_w + (((size_t)l * 16 + jlow) << 10);
    bf16x8 wfrag[8];
    #pragma unroll
    for (int i = 0; i < 8; ++i) {
        const int kf = (wid * 8 + i) * 32 + g * 8;
        wfrag[i] = cvt8(*(const float4*)(wrow + kf), *(const float4*)(wrow + kf + 4));
    }
    const float* w2row = l2_w + ((size_t)l * 32 + col32) * 16 + h * 8;
    const bf16x8 w2frag = cvt8(*(const float4*)(w2row), *(const float4*)(w2row + 4));
    float w3v[16], b2v[16];
    #pragma unroll
    for (int r = 0; r < 16; ++r) {
        int j2 = (r & 3) + 8 * (r >> 2) + 4 * h;
        w3v[r] = out_w[l * 32 + j2];
        b2v[r] = l2_b[l * 32 + j2];
    }
    const float l1bias = l1_b[l * 16 + jlow];
    const float outb   = out_b[l];

    const int srow  = tid >> 5;   // 0..7 (this thread stages rows srow, srow+8)
    const int scol8 = tid & 31;   // 8-float chunk lane
    const int pr    = tid >> 2;   // psq staging row (tid<64)
    const int ppart = tid & 3;    // psq staging quarter
    const int psf   = (ppart < 2) ? (512 + 4 * ppart) : (1032 + 4 * (ppart - 2));

    // ---- register prefetch buffers (tile t+1 in flight across compute) ----
    float4 pfa[8], pfb[8];        // 16 rows x this thread's 4 chunk-pairs
    float4 pfq;                   // psqt quarter (tid<64)
    float  us_nxt = 0.f; int pi_nxt = 0;   // epilogue gathers (wave0, lane<16)
    float  us_cur;       int pi_cur;

    // issue prefetch for tile starting at `tb` (clamped indices; safe reads)
    auto issue_pf = [&](int tb) {
        #pragma unroll
        for (int rr = 0; rr < 2; ++rr) {
            const int mi = tb + rr * 8 + srow;
            const float* src = accum + (size_t)list[mi < n ? mi : n - 1] * 1040;
            #pragma unroll
            for (int p = 0; p < 4; ++p) {
                const int sf = 8 * (scol8 + 32 * p) + (p >= 2 ? 8 : 0);
                pfa[rr * 4 + p] = *(const float4*)(src + sf);
                pfb[rr * 4 + p] = *(const float4*)(src + sf + 4);
            }
        }
        if (tid < 64) {
            const int mi = tb + pr;
            const float* src = accum + (size_t)list[mi < n ? mi : n - 1] * 1040;
            pfq = *(const float4*)(src + psf);
        }
        if (wid == 0 && lane < 16) {
            const int mi = tb + jlow;
            const int s  = list[mi < n ? mi : n - 1];
            us_nxt = us[s];
            pi_nxt = psqt_indices[s];
        }
    };

    issue_pf(0);

    int buf = 0;
    for (int tb = 0; tb < n; tb += 16, buf ^= 1) {
        // ---- stage: write prefetched tile to LDS (waits vmcnt on pf regs) ----
        #pragma unroll
        for (int rr = 0; rr < 2; ++rr) {
            const int row = rr * 8 + srow;
            #pragma unroll
            for (int p = 0; p < 4; ++p)
                *(bf16x8*)&At[row][8 * (scol8 + 32 * p)] = cvt8(pfa[rr * 4 + p], pfb[rr * 4 + p]);
        }
        if (tid < 64) *(float4*)&psq[buf][pr][ppart * 4] = pfq;
        __syncthreads();                       // At[tb], psq[buf] ready

        // ---- issue next tile's loads (stay in flight across compute) ----
        us_cur = us_nxt; pi_cur = pi_nxt;
        issue_pf(tb + 16);

        // ---- split-K MFMA over this wave's K-quarter ----
        f32x4 acc = {0.f, 0.f, 0.f, 0.f};
        #pragma unroll
        for (int i = 0; i < 8; ++i) {
            const int kf = (wid * 8 + i) * 32 + g * 8;
            bf16x8 afrag = *(const bf16x8*)&At[jlow][kf];
            acc = __builtin_amdgcn_mfma_f32_16x16x32_bf16(afrag, wfrag[i], acc, 0, 0, 0);
        }
        *(f32x4*)&l1part[wid][lane][0] = acc;
        __syncthreads();                       // l1part ready; At consumed

        if (wid == 0) {
            f32x4 t0 = *(const f32x4*)&l1part[0][lane][0];
            f32x4 t1 = *(const f32x4*)&l1part[1][lane][0];
            f32x4 t2 = *(const f32x4*)&l1part[2][lane][0];
            f32x4 t3 = *(const f32x4*)&l1part[3][lane][0];
            #pragma unroll
            for (int r = 0; r < 4; ++r) {
                float v = fminf(fmaxf(t0[r] + t1[r] + t2[r] + t3[r] + l1bias, 0.f), 1.f);
                l1y[(g * 4 + r) * 20 + jlow] = v;
            }
            __builtin_amdgcn_wave_barrier();
            asm volatile("s_waitcnt lgkmcnt(0)" ::: "memory");

            const float* lyr = l1y + (col32 & 15) * 20 + h * 8;
            float4 y0 = *(const float4*)(lyr);
            float4 y1 = *(const float4*)(lyr + 4);
            const bf16x8 b2frag = cvt8(y0, y1);

            f32x16 acc2 = {};
            acc2 = __builtin_amdgcn_mfma_f32_32x32x16_bf16(w2frag, b2frag, acc2, 0, 0, 0);

            float partial = 0.f;
            #pragma unroll
            for (int r = 0; r < 16; ++r) {
                float v = fminf(fmaxf(acc2[r] + b2v[r], 0.f), 1.f);
                partial += v * w3v[r];
            }
            partial += __shfl_xor(partial, 32);

            if (lane < 16 && tb + jlow < n) {
                const int s = list[tb + jlow];
                const float wp = psq[buf][jlow][pi_cur];
                const float bp = psq[buf][jlow][8 + pi_cur];
                out[s] = partial + outb + (wp - bp) * (us_cur - 0.5f);
            }
        }
        // no 3rd barrier: psq is double-buffered; next stage-write to At happens
        // only after the next __syncthreads-protected region entry below
        __syncthreads();                       // wave0 done with psq[buf]/l1part before overwrite
    }
}

extern "C" void kernel_launch(void* const* d_in, const int* in_sizes, int n_in,
                              void* d_out, int out_size, void* d_ws, size_t ws_size,
                              hipStream_t stream) {
    const float* accum = (const float*)d_in[0];
    const float* us    = (const float*)d_in[1];
    const float* l1_w  = (const float*)d_in[2];
    const float* l1_b  = (const float*)d_in[3];
    const float* l2_w  = (const float*)d_in[4];
    const float* l2_b  = (const float*)d_in[5];
    const float* out_w = (const float*)d_in[6];
    const float* out_b = (const float*)d_in[7];
    const int*   psqt  = (const int*)d_in[8];
    const int*   lsi   = (const int*)d_in[9];
    float* out = (float*)d_out;

    dim3 grid(B_TOTAL / W_WIN, NCOUNT);
    nnue_mfma_kernel<<<grid, BLK, 0, stream>>>(
        accum, us, l1_w, l1_b, l2_w, l2_b, out_w, out_b, psqt, lsi, out);
}